// Round 2
// baseline (669.875 us; speedup 1.0000x reference)
//
#include <hip/hip_runtime.h>
#include <hip/hip_bf16.h>

// SumPooling / segment_sum: out[s, d] = sum_{i: index[i]==s} x[i, d]
// x: (1e6, 128) fp32, index: (1e6,) sorted int32, out: (16384, 128) fp32.
//
// Structure: one 64-lane wave per 128-row chunk. Half-wave per row:
// lanes 0-31 handle even rows, lanes 32-63 odd rows; each lane owns a
// float4 (16B) column slice -> global_load_dwordx4, 1KB/wave/instr.
// 8 rows per unrolled step, 2-stage software pipeline (prefetch next
// step's loads before processing current). Index sorted -> run-length
// accumulate in registers, atomicAdd only at segment boundaries.

constexpr int D_FEAT = 128;
constexpr int D4 = D_FEAT / 4;            // 32 float4 per row
constexpr int ROWS_PER_WAVE = 128;
constexpr int WAVES_PER_BLOCK = 4;        // block = 256 threads

__global__ void zero_out_kernel(float4* __restrict__ out, int n4) {
    int i = blockIdx.x * blockDim.x + threadIdx.x;
    int stride = gridDim.x * blockDim.x;
    for (; i < n4; i += stride) {
        out[i] = make_float4(0.f, 0.f, 0.f, 0.f);
    }
}

__global__ __launch_bounds__(256) void segsum_kernel(
        const float* __restrict__ x,
        const int* __restrict__ index,
        float* __restrict__ out,
        int n_rows) {
    const int wave_in_block = threadIdx.x >> 6;
    const int lane = threadIdx.x & 63;
    const int half = lane >> 5;           // 0 = even rows, 1 = odd rows
    const int sub = lane & 31;            // which float4 of the row
    const long wave = (long)blockIdx.x * WAVES_PER_BLOCK + wave_in_block;

    long row0 = wave * ROWS_PER_WAVE;
    if (row0 >= n_rows) return;
    long rend = row0 + ROWS_PER_WAVE;
    if (rend > n_rows) rend = n_rows;

    const float4* __restrict__ x4 = (const float4*)x;

    float4 acc = make_float4(0.f, 0.f, 0.f, 0.f);
    long myrow0 = row0 + half;
    int cur_seg = index[myrow0 < rend ? myrow0 : (rend - 1)];

    auto flush = [&]() {
        float* o = out + (long)cur_seg * D_FEAT + (sub << 2);
        atomicAdd(o + 0, acc.x);
        atomicAdd(o + 1, acc.y);
        atomicAdd(o + 2, acc.z);
        atomicAdd(o + 3, acc.w);
    };
    auto step1 = [&](int s, const float4& v) {
        if (s != cur_seg) {               // half-wave-uniform branch
            flush();
            cur_seg = s;
            acc = v;
        } else {
            acc.x += v.x; acc.y += v.y; acc.z += v.z; acc.w += v.w;
        }
    };

    const long nmain = (rend - row0) >> 3;    // 8-row steps

    // my 4 rows per step: row0+half, +2, +4, +6  (stride 2 rows = 64 float4)
    const float4* p = x4 + (row0 + half) * D4 + sub;
    const int* ip = index + row0;

    float4 va0 = acc, va1 = acc, va2 = acc, va3 = acc;
    float4 vb0 = acc, vb1 = acc, vb2 = acc, vb3 = acc;
    int4 ia = make_int4(0, 0, 0, 0), ib = ia, ja = ia, jb = ia;

    if (nmain > 0) {
        ia = *(const int4*)(ip);
        ib = *(const int4*)(ip + 4);
        va0 = p[0]; va1 = p[64]; va2 = p[128]; va3 = p[192];
    }
    for (long t = 0; t < nmain; ++t) {
        if (t + 1 < nmain) {              // prefetch next step
            ja = *(const int4*)(ip + 8);
            jb = *(const int4*)(ip + 12);
            const float4* pn = p + 256;
            vb0 = pn[0]; vb1 = pn[64]; vb2 = pn[128]; vb3 = pn[192];
        }
        // this half's 4 segment ids for rows (r+half), (r+half+2), ...
        int s0 = half ? ia.y : ia.x;
        int s1 = half ? ia.w : ia.z;
        int s2 = half ? ib.y : ib.x;
        int s3 = half ? ib.w : ib.z;
        if (s0 == cur_seg && s3 == cur_seg) {
            // fast path: sorted => all 4 rows in cur_seg
            acc.x += (va0.x + va1.x) + (va2.x + va3.x);
            acc.y += (va0.y + va1.y) + (va2.y + va3.y);
            acc.z += (va0.z + va1.z) + (va2.z + va3.z);
            acc.w += (va0.w + va1.w) + (va2.w + va3.w);
        } else {
            step1(s0, va0); step1(s1, va1); step1(s2, va2); step1(s3, va3);
        }
        ia = ja; ib = jb;
        va0 = vb0; va1 = vb1; va2 = vb2; va3 = vb3;
        p += 256; ip += 8;
    }

    // tail (n_rows % 8 != 0 case): pairwise rows
    for (long r = row0 + nmain * 8; r < rend; r += 2) {
        long my_r = r + half;
        if (my_r < rend) {
            int s = index[my_r];
            float4 v = x4[my_r * D4 + sub];
            step1(s, v);
        }
    }
    flush();
}

extern "C" void kernel_launch(void* const* d_in, const int* in_sizes, int n_in,
                              void* d_out, int out_size, void* d_ws, size_t ws_size,
                              hipStream_t stream) {
    const float* x = (const float*)d_in[0];
    const int* index = (const int*)d_in[1];
    float* out = (float*)d_out;

    const int n_rows = in_sizes[1];           // 1,000,000
    const int n_out4 = out_size / 4;          // 16384*128/4

    zero_out_kernel<<<512, 256, 0, stream>>>((float4*)out, n_out4);

    const long n_waves = ((long)n_rows + ROWS_PER_WAVE - 1) / ROWS_PER_WAVE;
    const int n_blocks = (int)((n_waves + WAVES_PER_BLOCK - 1) / WAVES_PER_BLOCK);
    segsum_kernel<<<n_blocks, 256, 0, stream>>>(x, index, out, n_rows);
}